// Round 7
// baseline (121.356 us; speedup 1.0000x reference)
//
#include <hip/hip_runtime.h>

// Fused 9-layer MLP (3->128, 7x 128->128 ReLU, 128->3) over 262144 points.
// Round-7: persistent blocks + wave-stagger + no setprio.
//   - f16 RN weights x f16 RTZ activations, ONE MFMA per product (r6 numerics,
//     absmax 4.88e-4 bit-stable across rounds).
//   - Grid 256 (one block/CU), each block does 2 batches of 512 pts reusing
//     the LDS-resident weights: initial stage L0-L4+L8+bias once; P region
//     (3 layers) swaps L1-3 <-> L5-7 with the restage drain covered by
//     compute (L4 covers L5-7; L8+epilogue+xload covers L1-3).
//   - Wave-stagger: waves 4-7 s_sleep ~960cyc after each free-run barrier so
//     co-SIMD wave pairs run antiphase (split/LDS hides under partner's MFMA).
//   - s_setprio removed (m190: neutral/negative for lockstep GEMM).

typedef __attribute__((ext_vector_type(8)))  _Float16 f16x8;
typedef __attribute__((ext_vector_type(2)))  _Float16 f16x2;
typedef __attribute__((ext_vector_type(16))) float    floatx16;

#define BIAS_FLOATS 1152       // 9 layers * 4 mtiles * 2 g * 16 regs
#define WG_THREADS  512
#define PTS_PER_BLK 1024       // 2 batches x (8 waves * 64 points)

// Wpack 16B-slot layout: L0 slim | L1..L7 full | L8 slim
#define SLOT_L0   0            // 256 slots  (frag m: m*64 + lane)
#define SLOT_L1   256          // 7 * 2048 slots (frag (L,m,ks): L*2048 + (m*8+ks)*64 + lane)
#define SLOT_L4   6400
#define SLOT_L5   8448
#define SLOT_L8   14592        // 512 slots (frag ks: ks*64 + lane)
#define SLOTS_W   15104
#define BIAS_OFF_H 120832      // half-index of bias floats in ws (= SLOTS_W*8)

// LDS half-offsets
#define OFF_L0  0
#define OFF_P   2048           // L1,L2,L3 <-> L5,L6,L7 (3 * 16384 halves)
#define OFF_Q   51200          // L4 (resident)
#define OFF_L8  67584          // 4096 halves (resident)
#define LDS_W_H 71680

__global__ void pack_weights(const float* __restrict__ W0, const float* __restrict__ b0,
                             const float* __restrict__ Wh, const float* __restrict__ bhid,
                             const float* __restrict__ Wout, const float* __restrict__ bout,
                             unsigned short* __restrict__ Wpack, float* __restrict__ bias_pack)
{
    const int t = blockIdx.x * 256 + threadIdx.x;
    if (t < SLOTS_W) {
        float wv[8];
        if (t < SLOT_L1) {                         // L0 slim: 4 frags (m), k<3 live
            const int lane = t & 63, m = t >> 6;
            const int row = 32 * m + (lane & 31), g = lane >> 5;
#pragma unroll
            for (int j = 0; j < 8; ++j) {
                const int k = 4 * g + (j & 3) + 8 * (j >> 2);
                wv[j] = (k < 3) ? W0[row * 3 + k] : 0.0f;
            }
        } else if (t < SLOT_L8) {                  // L1..L7 full
            const int u = t - SLOT_L1;
            const int lane = u & 63, ks = (u >> 6) & 7, m = (u >> 9) & 3, L1 = u >> 11;
            const int row = 32 * m + (lane & 31), g = lane >> 5;
#pragma unroll
            for (int j = 0; j < 8; ++j) {
                const int k = 16 * ks + 4 * g + (j & 3) + 8 * (j >> 2);
                wv[j] = Wh[L1 * 16384 + row * 128 + k];
            }
        } else {                                   // L8 slim: m=0 tile, rows<3 live
            const int u = t - SLOT_L8;
            const int lane = u & 63, ks = u >> 6;
            const int row = lane & 31, g = lane >> 5;
#pragma unroll
            for (int j = 0; j < 8; ++j) {
                const int k = 16 * ks + 4 * g + (j & 3) + 8 * (j >> 2);
                wv[j] = (row < 3) ? Wout[row * 128 + k] : 0.0f;
            }
        }
        unsigned int ov[4];
#pragma unroll
        for (int jj = 0; jj < 4; ++jj) {
            const unsigned short e0 = __builtin_bit_cast(unsigned short, (_Float16)wv[2 * jj]);
            const unsigned short e1 = __builtin_bit_cast(unsigned short, (_Float16)wv[2 * jj + 1]);
            ov[jj] = (unsigned int)e0 | ((unsigned int)e1 << 16);
        }
        reinterpret_cast<uint4*>(Wpack)[t] = make_uint4(ov[0], ov[1], ov[2], ov[3]);
    } else if (t < SLOTS_W + BIAS_FLOATS) {
        const int i   = t - SLOTS_W;
        const int idx = i & 15;
        const int g   = (i >> 4) & 1;
        const int m   = (i >> 5) & 3;
        const int L   = i >> 7;
        const int row = 32 * m + (idx & 3) + 8 * (idx >> 2) + 4 * g;  // C/D row for reg=idx
        float v = 0.0f;
        if (L == 0)       v = b0[row];
        else if (L < 8)   v = bhid[(L - 1) * 128 + row];
        else if (row < 3) v = bout[row];
        bias_pack[i] = v;
    }
}

__device__ __forceinline__ void stage_range(const unsigned short* Wpack, unsigned short* Wl,
                                            int src_slot, int dst_half, int nslots, int tid)
{
    const char* gsrc = (const char*)Wpack + (size_t)src_slot * 16;
    char* ldst = (char*)Wl + (size_t)dst_half * 2;
    for (int i = tid; i < nslots; i += WG_THREADS) {
        __builtin_amdgcn_global_load_lds(
            (const __attribute__((address_space(1))) unsigned int*)(gsrc + i * 16),
            (__attribute__((address_space(3))) unsigned int*)(ldst + i * 16),
            16, 0, 0);
    }
}

// De-phase co-SIMD wave pairs (waves 0-3 and 4-7 share SIMDs pairwise under
// round-robin wave->SIMD assignment). ~960 cycles.
__device__ __forceinline__ void stagger(int wv)
{
    if (wv >= 4) __builtin_amdgcn_s_sleep(15);
}

union F16x8u { f16x8 v; f16x2 h[4]; };

// relu + packed RTZ f16 of one acc set -> next-layer B fragments.
#define PKRTZ(a, b) __builtin_bit_cast(f16x2, __builtin_amdgcn_cvt_pkrtz((a), (b)))
#define SPLIT1(accv, bv)                                                        \
    _Pragma("unroll")                                                           \
    for (int m = 0; m < 4; ++m) {                                               \
        F16x8u t0, t1;                                                          \
        _Pragma("unroll")                                                       \
        for (int q = 0; q < 4; ++q) {                                           \
            t0.h[q] = PKRTZ(fmaxf(accv[m][2 * q], 0.0f),                        \
                            fmaxf(accv[m][2 * q + 1], 0.0f));                   \
            t1.h[q] = PKRTZ(fmaxf(accv[m][8 + 2 * q], 0.0f),                    \
                            fmaxf(accv[m][9 + 2 * q], 0.0f));                   \
        }                                                                       \
        bv[2 * m]     = t0.v;                                                   \
        bv[2 * m + 1] = t1.v;                                                   \
    }

__device__ __forceinline__ floatx16 bias_init(const float* blds, int L, int m, int g)
{
    const float4* bp = (const float4*)&blds[((L * 4 + m) * 2 + g) * 16];
    const float4 b0v = bp[0], b1v = bp[1], b2v = bp[2], b3v = bp[3];
    floatx16 a;
    a[0] = b0v.x;  a[1] = b0v.y;  a[2] = b0v.z;  a[3] = b0v.w;
    a[4] = b1v.x;  a[5] = b1v.y;  a[6] = b1v.z;  a[7] = b1v.w;
    a[8] = b2v.x;  a[9] = b2v.y;  a[10] = b2v.z; a[11] = b2v.w;
    a[12] = b3v.x; a[13] = b3v.y; a[14] = b3v.z; a[15] = b3v.w;
    return a;
}

__device__ __forceinline__ void layer_full(const unsigned short* wb, const float* blds,
                                           int Lb, int g, int lane,
                                           f16x8 (&b1)[8], f16x8 (&b2)[8])
{
    floatx16 acc[4], acc2[4];
#pragma unroll
    for (int m = 0; m < 4; ++m) {
        acc[m]  = bias_init(blds, Lb, m, g);
        acc2[m] = acc[m];
    }
#pragma unroll
    for (int ks = 0; ks < 8; ++ks) {
#pragma unroll
        for (int m = 0; m < 4; ++m) {
            const f16x8 a = *(const f16x8*)&wb[(m * 8 + ks) * 512 + lane * 8];
            acc[m]  = __builtin_amdgcn_mfma_f32_32x32x16_f16(a, b1[ks], acc[m],  0, 0, 0);
            acc2[m] = __builtin_amdgcn_mfma_f32_32x32x16_f16(a, b2[ks], acc2[m], 0, 0, 0);
        }
    }
    SPLIT1(acc, b1)
    SPLIT1(acc2, b2)
}

__global__ __launch_bounds__(WG_THREADS, 2) void mlp_fused(
    const float* __restrict__ x, const unsigned short* __restrict__ Wpack,
    const float* __restrict__ bias_pack, float* __restrict__ out)
{
    __shared__ unsigned short Wl[LDS_W_H];          // 140 KiB weights
    __shared__ float blds[BIAS_FLOATS];             // 4.5 KiB bias
    __shared__ float bounce[WG_THREADS * 3];        // 6 KiB output bounce

    const int tid  = threadIdx.x;
    const int lane = tid & 63;
    const int wv   = tid >> 6;
    const int col  = lane & 31;
    const int g    = lane >> 5;

    // initial stage (once per persistent block): L0+L1-3, L4, L8, bias
    stage_range(Wpack, Wl, SLOT_L0, OFF_L0, 6400, tid);
    stage_range(Wpack, Wl, SLOT_L4, OFF_Q, 2048, tid);
    stage_range(Wpack, Wl, SLOT_L8, OFF_L8, 512, tid);
    for (int i = tid; i < BIAS_FLOATS; i += WG_THREADS) blds[i] = bias_pack[i];

#pragma unroll
    for (int b = 0; b < 2; ++b) {
        const long pt = (long)blockIdx.x * PTS_PER_BLK + b * 512 + wv * 64 + col;

        // x -> layer0 B fragments (registers; independent of LDS state)
        f16x8 b1[8], b2[8];
        {
            f16x8 z1 = {(_Float16)0, (_Float16)0, (_Float16)0, (_Float16)0,
                        (_Float16)0, (_Float16)0, (_Float16)0, (_Float16)0};
            f16x8 z2 = z1;
            if (g == 0) {                           // k=0..2 live (j=0..2)
                const float* xp1 = x + pt * 3;
                const float* xp2 = x + (pt + 32) * 3;
#pragma unroll
                for (int c = 0; c < 3; ++c) {
                    z1[c] = (_Float16)xp1[c];
                    z2[c] = (_Float16)xp2[c];
                }
            }
            b1[0] = z1;
            b2[0] = z2;
        }

        __syncthreads();        // b=0: initial stage visible; b=1: L1-3 restage visible
        stagger(wv);

        // ---------------- layer 0 (single K=16 step, slim layout) ----------------
        {
            floatx16 acc[4], acc2[4];
#pragma unroll
            for (int m = 0; m < 4; ++m) {
                acc[m]  = bias_init(blds, 0, m, g);
                acc2[m] = acc[m];
            }
#pragma unroll
            for (int m = 0; m < 4; ++m) {
                const f16x8 a = *(const f16x8*)&Wl[OFF_L0 + m * 512 + lane * 8];
                acc[m]  = __builtin_amdgcn_mfma_f32_32x32x16_f16(a, b1[0], acc[m],  0, 0, 0);
                acc2[m] = __builtin_amdgcn_mfma_f32_32x32x16_f16(a, b2[0], acc2[m], 0, 0, 0);
            }
            SPLIT1(acc, b1)
            SPLIT1(acc2, b2)
        }

        // ---------------- layers 1..3: free-run ----------------
#pragma unroll
        for (int L = 1; L <= 3; ++L)
            layer_full(&Wl[OFF_P + (L - 1) * 16384], blds, L, g, lane, b1, b2);

        __syncthreads();        // all waves done reading P(L1-3)

        stage_range(Wpack, Wl, SLOT_L5, OFF_P, 6144, tid);  // P <- L5-7 (covered by L4)

        layer_full(&Wl[OFF_Q], blds, 4, g, lane, b1, b2);   // L4

        __syncthreads();        // L5-7 visible
        stagger(wv);

        // ---------------- layers 5..7: free-run ----------------
#pragma unroll
        for (int L = 5; L <= 7; ++L)
            layer_full(&Wl[OFF_P + (L - 5) * 16384], blds, L, g, lane, b1, b2);

        if (b == 0) {
            __syncthreads();    // all waves done reading P(L5-7)
            stage_range(Wpack, Wl, SLOT_L1, OFF_P, 6144, tid);  // P <- L1-3 for batch 1
            // drain covered by L8 + epilogue + next batch's x-load; synced at loop-top barrier
        }

        // ---------------- output layer (L=8, m=0 tile, rows 0..2 valid) ----------------
        floatx16 o1 = bias_init(blds, 8, 0, g);
        floatx16 o2 = o1;
#pragma unroll
        for (int ks = 0; ks < 8; ++ks) {
            const f16x8 a = *(const f16x8*)&Wl[OFF_L8 + ks * 512 + lane * 8];
            o1 = __builtin_amdgcn_mfma_f32_32x32x16_f16(a, b1[ks], o1, 0, 0, 0);
            o2 = __builtin_amdgcn_mfma_f32_32x32x16_f16(a, b2[ks], o2, 0, 0, 0);
        }

        // ---------------- epilogue: LDS bounce for coalesced stores ----------------
        {
            const int wb = wv * 192;                // per-wave private 192 floats
            if (g == 0) {
                bounce[wb + col * 3 + 0] = o1[0];
                bounce[wb + col * 3 + 1] = o1[1];
                bounce[wb + col * 3 + 2] = o1[2];
                bounce[wb + (32 + col) * 3 + 0] = o2[0];
                bounce[wb + (32 + col) * 3 + 1] = o2[1];
                bounce[wb + (32 + col) * 3 + 2] = o2[2];
            }
            // wave-internal LDS dependency: compiler inserts lgkmcnt wait
            float* ob = out + ((long)blockIdx.x * PTS_PER_BLK + b * 512) * 3 + wb;
#pragma unroll
            for (int s = 0; s < 3; ++s)
                ob[s * 64 + lane] = bounce[wb + s * 64 + lane];
        }
    }
}

extern "C" void kernel_launch(void* const* d_in, const int* in_sizes, int n_in,
                              void* d_out, int out_size, void* d_ws, size_t ws_size,
                              hipStream_t stream)
{
    const float* x    = (const float*)d_in[0];
    const float* W0   = (const float*)d_in[1];
    const float* b0   = (const float*)d_in[2];
    const float* Wh   = (const float*)d_in[3];
    const float* bh   = (const float*)d_in[4];
    const float* Wout = (const float*)d_in[5];
    const float* bout = (const float*)d_in[6];
    float* out = (float*)d_out;

    unsigned short* Wpack = (unsigned short*)d_ws;                       // 241664 B
    float* bias_pack = (float*)((char*)d_ws + (size_t)BIAS_OFF_H * 2);   // + 4608 B

    const int N = in_sizes[0] / 3;                  // 262144
    const int packThreads = SLOTS_W + BIAS_FLOATS;  // 16256

    hipLaunchKernelGGL(pack_weights, dim3((packThreads + 255) / 256), dim3(256), 0, stream,
                       W0, b0, Wh, bh, Wout, bout, Wpack, bias_pack);
    hipLaunchKernelGGL(mlp_fused, dim3(N / PTS_PER_BLK), dim3(WG_THREADS), 0, stream,
                       x, Wpack, bias_pack, out);
}